// Round 18
// baseline (278.318 us; speedup 1.0000x reference)
//
#include <hip/hip_runtime.h>
#include <hip/hip_bf16.h>

#define BATCH 65536
#define DIN   128
#define DH    512
#define DOUT  128
#define ROWS  32

typedef __attribute__((ext_vector_type(4))) float f32x4;
typedef __attribute__((ext_vector_type(8))) short s16x8;

__device__ __forceinline__ ushort f32_to_bf16_rn(float f) {
    uint32_t u = __float_as_uint(f);
    uint32_t r = (u + 0x7FFFu + ((u >> 16) & 1u)) >> 16;
    return (ushort)r;
}
__device__ __forceinline__ float bf16_to_f32(ushort h) {
    return __uint_as_float(((uint32_t)h) << 16);
}
__device__ __forceinline__ f32x4 mfma16(s16x8 a, s16x8 b, f32x4 c) {
    return __builtin_amdgcn_mfma_f32_16x16x32_bf16(a, b, c, 0, 0, 0);
}
// two f32x4 -> one s16x8 (plain bf16 RN; tolerance 8.0 >> bf16 GEMM error)
__device__ __forceinline__ s16x8 cvt8(f32x4 v0, f32x4 v1) {
    s16x8 r;
#pragma unroll
    for (int j = 0; j < 4; ++j) r[j] = (short)f32_to_bf16_rn(v0[j]);
#pragma unroll
    for (int j = 0; j < 4; ++j) r[4 + j] = (short)f32_to_bf16_rn(v1[j]);
    return r;
}

// ---------------------------------------------------------------------------
// prep: blk0 softmax(a); blk1..64 split B,C -> bf16 frag-linear. [verified]
// perm[(f*64+lane)*8+j] = M[k][col], k = ks*32+(lane>>4)*8+j,
// col = cg*16+(lane&15). B: f=cg*4+ks (cg<32). C: f=cg*16+ksg (cg<8,ksg<16).
// ---------------------------------------------------------------------------
__global__ void prep_kernel(const float* __restrict__ a,
                            const float* __restrict__ b,
                            const float* __restrict__ c,
                            float* __restrict__ decay,
                            ushort* __restrict__ bhi,
                            ushort* __restrict__ chi)
{
    const int t = threadIdx.x;
    if (blockIdx.x == 0) {
        __shared__ float red[256];
        float v0 = a[t], v1 = a[t + 256];
        red[t] = fmaxf(v0, v1);
        __syncthreads();
        for (int s = 128; s > 0; s >>= 1) {
            if (t < s) red[t] = fmaxf(red[t], red[t + s]);
            __syncthreads();
        }
        float M = red[0];
        __syncthreads();
        float e0 = expf(v0 - M), e1 = expf(v1 - M);
        red[t] = e0 + e1;
        __syncthreads();
        for (int s = 128; s > 0; s >>= 1) {
            if (t < s) red[t] += red[t + s];
            __syncthreads();
        }
        float S = red[0];
        decay[t]       = e0 / S;
        decay[t + 256] = e1 / S;
    } else {
        const int p = (blockIdx.x - 1) * 256 + t;
        const int mtx = p >> 13;
        const int q = p & 8191;
        const int f = q >> 6;
        const int l = q & 63;
        s16x8 hi;
        if (mtx == 0) {
            const int cg = f >> 2, ks = f & 3;
            const int col = cg * 16 + (l & 15);
            const int kbase = ks * 32 + (l >> 4) * 8;
#pragma unroll
            for (int j = 0; j < 8; ++j)
                hi[j] = (short)f32_to_bf16_rn(b[(size_t)(kbase + j) * DH + col]);
            *(s16x8*)(bhi + (size_t)q * 8) = hi;
        } else {
            const int cg = f >> 4, ks = f & 15;
            const int col = cg * 16 + (l & 15);
            const int kbase = ks * 32 + (l >> 4) * 8;
#pragma unroll
            for (int j = 0; j < 8; ++j)
                hi[j] = (short)f32_to_bf16_rn(c[(size_t)(kbase + j) * DOUT + col]);
            *(s16x8*)(chi + (size_t)q * 8) = hi;
        }
    }
}

// ---------------------------------------------------------------------------
// fused v13: v12 byte-identical EXCEPT __launch_bounds__(256,8).
// Resources (measured v12): VGPR 64, SGPR 32, LDS 16KB -> 8 blocks/CU fit
// (8x16KB=128KB LDS, VGPR 64 = 8 waves/SIMD). v12's (256,4) capped us at
// 4 blocks/CU / 38% occupancy; this doubles independent block-streams.
// Per chunk (unchanged): cF issued first (covered by GEMM1+epilogue);
// GEMM1 u@B from bF regs; B(ct+1)+x(ct+1) issued pre-barrier; epilogue
// xn = acc1+dv*x + X<-bf16; ONE __syncthreads; GEMM2 X@C from cF regs.
// ---------------------------------------------------------------------------
__global__ __launch_bounds__(256, 8)
void rnn_fused(const float* __restrict__ u, const float* __restrict__ x,
               const float* __restrict__ decay,
               const ushort* __restrict__ bhi, const ushort* __restrict__ chi,
               float* __restrict__ xn, float* __restrict__ out)
{
    __shared__ __align__(16) char smem[16384];
    ushort* Ah = (ushort*)smem;             // [32][128] bf16, swz, 8KB

    const int t = threadIdx.x;
    const int lane = t & 63, wc = t >> 6;
    const int cl = lane & 15, hk = lane >> 4;
    const int row0 = blockIdx.x * ROWS;

    {   // stage A: u[32][128] f32 -> bf16 swizzled; 64B/thread coalesced
        const int r = t >> 3;
        const int kb = (t & 7) * 2;
#pragma unroll
        for (int i = 0; i < 2; ++i) {
            const float* src = u + (size_t)(row0 + r) * DIN + (kb + i) * 8;
            f32x4 v0 = *(const f32x4*)src;
            f32x4 v1 = *(const f32x4*)(src + 4);
            const int byte = (r * 256 + (kb + i) * 16) ^ ((r & 7) << 4);
            *(s16x8*)((char*)Ah + byte) = cvt8(v0, v1);
        }
    }

    // prologue: bF = B(0) frags; xv = x(0); dvc = decay(0)   (batched issue)
    s16x8 bF[4], bFn[4];
#pragma unroll
    for (int ks = 0; ks < 4; ++ks)
        bF[ks] = *(const s16x8*)(bhi + (size_t)(wc * 4 + ks) * 512 + lane * 8);

    float xv[2][4], xvn[2][4], dvc, dvn;
    dvc = decay[wc * 16 + cl];
#pragma unroll
    for (int mf = 0; mf < 2; ++mf)
#pragma unroll
        for (int j = 0; j < 4; ++j)
            xv[mf][j] = x[(size_t)(row0 + mf * 16 + 4 * hk + j) * DH + wc * 16 + cl];

    __syncthreads();   // A visible

    f32x4 acc2[2][2];
#pragma unroll
    for (int mf = 0; mf < 2; ++mf)
#pragma unroll
        for (int nf = 0; nf < 2; ++nf)
            acc2[mf][nf] = (f32x4){0.f, 0.f, 0.f, 0.f};

    for (int ct = 0; ct < 8; ++ct) {
        char* Xh = smem + 8192 + (ct & 1) * 4096;   // [32][64] bf16, swz

        // ---- issue C(ct) frag loads FIRST (consumed at chunk end)
        s16x8 cF[2][2];
#pragma unroll
        for (int ks2 = 0; ks2 < 2; ++ks2)
#pragma unroll
            for (int nf = 0; nf < 2; ++nf)
                cF[ks2][nf] = *(const s16x8*)(chi +
                    (size_t)((wc * 2 + nf) * 16 + ct * 2 + ks2) * 512 + lane * 8);

        // ---- GEMM1: acc1 = u @ B-chunk from bF regs (LDS A + MFMA only)
        f32x4 acc1[2];
        acc1[0] = (f32x4){0.f, 0.f, 0.f, 0.f};
        acc1[1] = (f32x4){0.f, 0.f, 0.f, 0.f};
#pragma unroll
        for (int ks = 0; ks < 4; ++ks) {
            const int ko = ks * 32 + hk * 8;
            s16x8 ah[2];
#pragma unroll
            for (int mf = 0; mf < 2; ++mf) {
                const int r = mf * 16 + cl;
                const int byte = (r * 256 + ko * 2) ^ ((r & 7) << 4);
                ah[mf] = *(const s16x8*)((const char*)Ah + byte);
            }
#pragma unroll
            for (int mf = 0; mf < 2; ++mf) acc1[mf] = mfma16(ah[mf], bF[ks], acc1[mf]);
        }

        // ---- issue B(ct+1) + x(ct+1) BEFORE the barrier (in flight across)
        if (ct < 7) {
#pragma unroll
            for (int ks = 0; ks < 4; ++ks)
                bFn[ks] = *(const s16x8*)(bhi +
                    (size_t)(((ct + 1) * 4 + wc) * 4 + ks) * 512 + lane * 8);
            const int ncol = (ct + 1) * 64 + wc * 16 + cl;
            dvn = decay[ncol];
#pragma unroll
            for (int mf = 0; mf < 2; ++mf)
#pragma unroll
                for (int j = 0; j < 4; ++j)
                    xvn[mf][j] = x[(size_t)(row0 + mf * 16 + 4 * hk + j) * DH + ncol];
        }

        // ---- epilogue: xn = acc1 + dv*x; X[ct&1] <- bf16 (swz LDS)
        {
            const int col = ct * 64 + wc * 16 + cl;
#pragma unroll
            for (int mf = 0; mf < 2; ++mf) {
#pragma unroll
                for (int j = 0; j < 4; ++j) {
                    const int rl = mf * 16 + 4 * hk + j;
                    const float v = acc1[mf][j] + dvc * xv[mf][j];
                    xn[(size_t)(row0 + rl) * DH + col] = v;
                    const int cbyte = (rl * 128 + (wc * 16 + cl) * 2) ^ ((rl & 7) << 4);
                    *(ushort*)(Xh + cbyte) = f32_to_bf16_rn(v);
                }
            }
        }

        __syncthreads();   // single barrier: X[ct&1] visible to all waves

        // ---- GEMM2: acc2 += X @ C-chunk from cF regs
#pragma unroll
        for (int ks2 = 0; ks2 < 2; ++ks2) {
            const int ko = ks2 * 32 + hk * 8;
            s16x8 ah2[2];
#pragma unroll
            for (int mf = 0; mf < 2; ++mf) {
                const int r = mf * 16 + cl;
                const int byte = (r * 128 + ko * 2) ^ ((r & 7) << 4);
                ah2[mf] = *(const s16x8*)((const char*)Xh + byte);
            }
#pragma unroll
            for (int nf = 0; nf < 2; ++nf)
#pragma unroll
                for (int mf = 0; mf < 2; ++mf)
                    acc2[mf][nf] = mfma16(ah2[mf], cF[ks2][nf], acc2[mf][nf]);
        }

        // ---- rotate prefetched state
#pragma unroll
        for (int ks = 0; ks < 4; ++ks) bF[ks] = bFn[ks];
        dvc = dvn;
#pragma unroll
        for (int mf = 0; mf < 2; ++mf)
#pragma unroll
            for (int j = 0; j < 4; ++j) xv[mf][j] = xvn[mf][j];
    }

    // ---- final: store out[32 x 128]; wave covers cols [wc*32, +32)
#pragma unroll
    for (int nf = 0; nf < 2; ++nf) {
        const int ocol = wc * 32 + nf * 16 + cl;
#pragma unroll
        for (int mf = 0; mf < 2; ++mf) {
#pragma unroll
            for (int j = 0; j < 4; ++j) {
                const int rl = mf * 16 + 4 * hk + j;
                out[(size_t)(row0 + rl) * DOUT + ocol] = acc2[mf][nf][j];
            }
        }
    }
}

extern "C" void kernel_launch(void* const* d_in, const int* in_sizes, int n_in,
                              void* d_out, int out_size, void* d_ws, size_t ws_size,
                              hipStream_t stream)
{
    const float* x = (const float*)d_in[0];
    const float* u = (const float*)d_in[1];
    const float* a = (const float*)d_in[2];
    const float* b = (const float*)d_in[3];
    const float* c = (const float*)d_in[4];

    float* xn  = (float*)d_out;                       // [BATCH][DH]
    float* out = xn + (size_t)BATCH * DH;             // [BATCH][DOUT]

    char* ws = (char*)d_ws;
    float*  decay = (float*)ws;                       // 512 f32
    ushort* bhi = (ushort*)(ws + 4096);               // 128KB frag-linear B
    ushort* chi = bhi + 128 * 512;                    // 128KB frag-linear C

    prep_kernel<<<dim3(65), dim3(256), 0, stream>>>(a, b, c, decay, bhi, chi);
    rnn_fused<<<dim3(BATCH / ROWS), dim3(256), 0, stream>>>(u, x, decay, bhi, chi, xn, out);
}

// Round 19
// 136.718 us; speedup vs baseline: 2.0357x; 2.0357x over previous
//
#include <hip/hip_runtime.h>
#include <hip/hip_bf16.h>

#define BATCH 65536
#define DIN   128
#define DH    512
#define DOUT  128
#define ROWS  32

typedef __attribute__((ext_vector_type(4))) float f32x4;
typedef __attribute__((ext_vector_type(8))) short s16x8;

__device__ __forceinline__ ushort f32_to_bf16_rn(float f) {
    uint32_t u = __float_as_uint(f);
    uint32_t r = (u + 0x7FFFu + ((u >> 16) & 1u)) >> 16;
    return (ushort)r;
}
__device__ __forceinline__ float bf16_to_f32(ushort h) {
    return __uint_as_float(((uint32_t)h) << 16);
}
__device__ __forceinline__ f32x4 mfma16(s16x8 a, s16x8 b, f32x4 c) {
    return __builtin_amdgcn_mfma_f32_16x16x32_bf16(a, b, c, 0, 0, 0);
}
__device__ __forceinline__ s16x8 cvt8(f32x4 v0, f32x4 v1) {
    s16x8 r;
#pragma unroll
    for (int j = 0; j < 4; ++j) r[j] = (short)f32_to_bf16_rn(v0[j]);
#pragma unroll
    for (int j = 0; j < 4; ++j) r[4 + j] = (short)f32_to_bf16_rn(v1[j]);
    return r;
}

// ---------------------------------------------------------------------------
// prep1: blk0 softmax; blk1..64 B,C -> bf16 frag-linear [verified R12];
// blk65..128 bcf = b@c (f32).
// perm[(f*64+lane)*8+j] = M[k][col], k = ks*32+(lane>>4)*8+j,
// col = cg*16+(lane&15). B: f=cg*4+ks (cg<32). C: f=cg*16+ksg (cg<8,ksg<16).
// ---------------------------------------------------------------------------
__global__ void prep1_kernel(const float* __restrict__ a,
                             const float* __restrict__ b,
                             const float* __restrict__ c,
                             float* __restrict__ decay,
                             ushort* __restrict__ bhi,
                             ushort* __restrict__ chi,
                             float* __restrict__ bcf)
{
    const int t = threadIdx.x;
    if (blockIdx.x == 0) {
        __shared__ float red[256];
        float v0 = a[t], v1 = a[t + 256];
        red[t] = fmaxf(v0, v1);
        __syncthreads();
        for (int s = 128; s > 0; s >>= 1) {
            if (t < s) red[t] = fmaxf(red[t], red[t + s]);
            __syncthreads();
        }
        float M = red[0];
        __syncthreads();
        float e0 = expf(v0 - M), e1 = expf(v1 - M);
        red[t] = e0 + e1;
        __syncthreads();
        for (int s = 128; s > 0; s >>= 1) {
            if (t < s) red[t] += red[t + s];
            __syncthreads();
        }
        float S = red[0];
        decay[t]       = e0 / S;
        decay[t + 256] = e1 / S;
    } else if (blockIdx.x <= 64) {
        const int p = (blockIdx.x - 1) * 256 + t;
        const int mtx = p >> 13;
        const int q = p & 8191;
        const int f = q >> 6;
        const int l = q & 63;
        s16x8 hi;
        if (mtx == 0) {
            const int cg = f >> 2, ks = f & 3;
            const int col = cg * 16 + (l & 15);
            const int kbase = ks * 32 + (l >> 4) * 8;
#pragma unroll
            for (int j = 0; j < 8; ++j)
                hi[j] = (short)f32_to_bf16_rn(b[(size_t)(kbase + j) * DH + col]);
            *(s16x8*)(bhi + (size_t)q * 8) = hi;
        } else {
            const int cg = f >> 4, ks = f & 15;
            const int col = cg * 16 + (l & 15);
            const int kbase = ks * 32 + (l >> 4) * 8;
#pragma unroll
            for (int j = 0; j < 8; ++j)
                hi[j] = (short)f32_to_bf16_rn(c[(size_t)(kbase + j) * DOUT + col]);
            *(s16x8*)(chi + (size_t)q * 8) = hi;
        }
    } else {
        // bc = b @ c (f32); one output/thread, c reads L2-hot
        const int i = (blockIdx.x - 65) * 2 + (t >> 7);
        const int j = t & 127;
        float acc = 0.f;
        for (int k = 0; k < DH; ++k)
            acc = fmaf(b[(size_t)i * DH + k], c[(size_t)k * DOUT + j], acc);
        bcf[i * DOUT + j] = acc;
    }
}

// prep2: bcf -> bf16 frag-linear (K=128: f = cg*4+ks, cg<8)  [verified R12]
__global__ void prep2_kernel(const float* __restrict__ bcf,
                             ushort* __restrict__ bch)
{
    const int p = blockIdx.x * 256 + threadIdx.x;   // [0, 2048)
    const int f = p >> 6, l = p & 63;
    const int cg = f >> 2, ks = f & 3;
    const int col = cg * 16 + (l & 15);
    const int kbase = ks * 32 + (l >> 4) * 8;
    s16x8 hi;
#pragma unroll
    for (int j = 0; j < 8; ++j)
        hi[j] = (short)f32_to_bf16_rn(bcf[(size_t)(kbase + j) * DOUT + col]);
    *(s16x8*)(bch + (size_t)p * 8) = hi;
}

// ---------------------------------------------------------------------------
// fused v14: TASK-PARALLEL split via bc-algebra (xn and out independent).
// Grid 4096; even blocks = k1 (xn = u@b + dv*x), odd = k2
// (out = (dv*x)@c + u@bc). Both 32 rows, 4 waves. LDS union 40KB -> 4
// blocks/CU, k1+k2 blocks co-resident (uncorrelated stall streams).
// k1: A-stage + 1 barrier, then wave-independent chunk loop (B-frag and
//     x prefetched one chunk ahead; no per-chunk barriers, no X/GEMM2).
// k2: stage Au + full X[32][512]=bf16(dv*x) (coalesced), 1 barrier, pure
//     K=512 GEMM from LDS (C-frags L2) + u@bc (K=128), C/D store.
// ---------------------------------------------------------------------------
__global__ __launch_bounds__(256, 4)
void rnn_fused(const float* __restrict__ u, const float* __restrict__ x,
               const float* __restrict__ decay,
               const ushort* __restrict__ bhi, const ushort* __restrict__ chi,
               const ushort* __restrict__ bch,
               float* __restrict__ xn, float* __restrict__ out)
{
    __shared__ __align__(16) char smem[40960];

    const int t = threadIdx.x;
    const int lane = t & 63, wc = t >> 6;
    const int cl = lane & 15, hk = lane >> 4;
    const int rb = blockIdx.x >> 1;
    const int row0 = rb * ROWS;

    if ((blockIdx.x & 1) == 0) {
        // ================= k1: xn = u@b + decay*x =================
        ushort* Ah = (ushort*)smem;          // [32][128] bf16, swz, 8KB
        {   // stage A (coalesced 64B/thread)
            const int r = t >> 3;
            const int kb = (t & 7) * 2;
#pragma unroll
            for (int i = 0; i < 2; ++i) {
                const float* src = u + (size_t)(row0 + r) * DIN + (kb + i) * 8;
                f32x4 v0 = *(const f32x4*)src;
                f32x4 v1 = *(const f32x4*)(src + 4);
                const int byte = (r * 256 + (kb + i) * 16) ^ ((r & 7) << 4);
                *(s16x8*)((char*)Ah + byte) = cvt8(v0, v1);
            }
        }

        // prologue: B(0) frags + x(0) + decay(0)
        s16x8 bF[4], bFn[4];
#pragma unroll
        for (int ks = 0; ks < 4; ++ks)
            bF[ks] = *(const s16x8*)(bhi + (size_t)(wc * 4 + ks) * 512 + lane * 8);
        float xv[2][4], xvn[2][4], dvc, dvn;
        dvc = decay[wc * 16 + cl];
#pragma unroll
        for (int mf = 0; mf < 2; ++mf)
#pragma unroll
            for (int j = 0; j < 4; ++j)
                xv[mf][j] = x[(size_t)(row0 + mf * 16 + 4 * hk + j) * DH + wc * 16 + cl];

        __syncthreads();   // the ONLY k1 barrier (A visible)

        for (int ct = 0; ct < 8; ++ct) {
            // issue next chunk's B + x first (hides under GEMM1 + stores)
            if (ct < 7) {
#pragma unroll
                for (int ks = 0; ks < 4; ++ks)
                    bFn[ks] = *(const s16x8*)(bhi +
                        (size_t)(((ct + 1) * 4 + wc) * 4 + ks) * 512 + lane * 8);
                const int ncol = (ct + 1) * 64 + wc * 16 + cl;
                dvn = decay[ncol];
#pragma unroll
                for (int mf = 0; mf < 2; ++mf)
#pragma unroll
                    for (int j = 0; j < 4; ++j)
                        xvn[mf][j] = x[(size_t)(row0 + mf * 16 + 4 * hk + j) * DH + ncol];
            }

            // GEMM1: acc1 = u @ B-chunk (wave cols = (ct*4+wc)*16 .. +16)
            f32x4 acc1[2];
            acc1[0] = (f32x4){0.f, 0.f, 0.f, 0.f};
            acc1[1] = (f32x4){0.f, 0.f, 0.f, 0.f};
#pragma unroll
            for (int ks = 0; ks < 4; ++ks) {
                const int ko = ks * 32 + hk * 8;
                s16x8 ah[2];
#pragma unroll
                for (int mf = 0; mf < 2; ++mf) {
                    const int r = mf * 16 + cl;
                    const int byte = (r * 256 + ko * 2) ^ ((r & 7) << 4);
                    ah[mf] = *(const s16x8*)((const char*)Ah + byte);
                }
#pragma unroll
                for (int mf = 0; mf < 2; ++mf) acc1[mf] = mfma16(ah[mf], bF[ks], acc1[mf]);
            }

            // xn = acc1 + dv*x (64B-line-complete per 16-lane group)
            {
                const int col = ct * 64 + wc * 16 + cl;
#pragma unroll
                for (int mf = 0; mf < 2; ++mf)
#pragma unroll
                    for (int j = 0; j < 4; ++j)
                        xn[(size_t)(row0 + mf * 16 + 4 * hk + j) * DH + col] =
                            acc1[mf][j] + dvc * xv[mf][j];
            }

            // rotate
#pragma unroll
            for (int ks = 0; ks < 4; ++ks) bF[ks] = bFn[ks];
            dvc = dvn;
#pragma unroll
            for (int mf = 0; mf < 2; ++mf)
#pragma unroll
                for (int j = 0; j < 4; ++j) xv[mf][j] = xvn[mf][j];
        }
    } else {
        // ============ k2: out = (decay*x)@c + u@bc ============
        ushort* Au = (ushort*)smem;          // [32][128] bf16, swz, 8KB
        char*   Xs = smem + 8192;            // [32][512] bf16, swz, 32KB

        {   // stage Au (coalesced)
            const int r = t >> 3;
            const int kb = (t & 7) * 2;
#pragma unroll
            for (int i = 0; i < 2; ++i) {
                const float* src = u + (size_t)(row0 + r) * DIN + (kb + i) * 8;
                f32x4 v0 = *(const f32x4*)src;
                f32x4 v1 = *(const f32x4*)(src + 4);
                const int byte = (r * 256 + (kb + i) * 16) ^ ((r & 7) << 4);
                *(s16x8*)((char*)Au + byte) = cvt8(v0, v1);
            }
        }
        {   // stage Xs = bf16(decay*x), full width, coalesced 64B/thread/chunk
            const int r2 = t >> 3;
            const int c0 = (t & 7) * 8;
            const float* xrow = x + (size_t)(row0 + r2) * DH + c0;
#pragma unroll
            for (int ct = 0; ct < 8; ++ct) {
                const int col = ct * 64 + c0;
                f32x4 v0 = *(const f32x4*)(xrow + ct * 64);
                f32x4 v1 = *(const f32x4*)(xrow + ct * 64 + 4);
                const f32x4 d0 = *(const f32x4*)&decay[col];
                const f32x4 d1 = *(const f32x4*)&decay[col + 4];
                const int byte = (r2 * 1024 + col * 2) ^ ((r2 & 7) << 4);
                *(s16x8*)(Xs + byte) = cvt8(v0 * d0, v1 * d1);
            }
        }
        __syncthreads();   // Au + Xs visible

        f32x4 acc[2][2];
#pragma unroll
        for (int mf = 0; mf < 2; ++mf)
#pragma unroll
            for (int nf = 0; nf < 2; ++nf)
                acc[mf][nf] = (f32x4){0.f, 0.f, 0.f, 0.f};

        // (decay*x) @ c : K = 512, 16 k-steps, C-frags from L2
#pragma unroll
        for (int ksg = 0; ksg < 16; ++ksg) {
            const int ko = ksg * 32 + hk * 8;
            s16x8 ah[2];
#pragma unroll
            for (int mf = 0; mf < 2; ++mf) {
                const int r = mf * 16 + cl;
                const int byte = (r * 1024 + ko * 2) ^ ((r & 7) << 4);
                ah[mf] = *(const s16x8*)(Xs + byte);
            }
#pragma unroll
            for (int nf = 0; nf < 2; ++nf) {
                const s16x8 cF = *(const s16x8*)(chi +
                    (size_t)((wc * 2 + nf) * 16 + ksg) * 512 + lane * 8);
#pragma unroll
                for (int mf = 0; mf < 2; ++mf)
                    acc[mf][nf] = mfma16(ah[mf], cF, acc[mf][nf]);
            }
        }

        // + u @ bc : K = 128
#pragma unroll
        for (int ks = 0; ks < 4; ++ks) {
            const int ko = ks * 32 + hk * 8;
            s16x8 ah[2];
#pragma unroll
            for (int mf = 0; mf < 2; ++mf) {
                const int r = mf * 16 + cl;
                const int byte = (r * 256 + ko * 2) ^ ((r & 7) << 4);
                ah[mf] = *(const s16x8*)((const char*)Au + byte);
            }
#pragma unroll
            for (int nf = 0; nf < 2; ++nf) {
                const s16x8 bcF = *(const s16x8*)(bch +
                    (size_t)((wc * 2 + nf) * 4 + ks) * 512 + lane * 8);
#pragma unroll
                for (int mf = 0; mf < 2; ++mf)
                    acc[mf][nf] = mfma16(ah[mf], bcF, acc[mf][nf]);
            }
        }

        // store out[32 x 128]; wave cols [wc*32, +32)
#pragma unroll
        for (int nf = 0; nf < 2; ++nf) {
            const int ocol = wc * 32 + nf * 16 + cl;
#pragma unroll
            for (int mf = 0; mf < 2; ++mf)
#pragma unroll
                for (int j = 0; j < 4; ++j)
                    out[(size_t)(row0 + mf * 16 + 4 * hk + j) * DOUT + ocol] =
                        acc[mf][nf][j];
        }
    }
}

extern "C" void kernel_launch(void* const* d_in, const int* in_sizes, int n_in,
                              void* d_out, int out_size, void* d_ws, size_t ws_size,
                              hipStream_t stream)
{
    const float* x = (const float*)d_in[0];
    const float* u = (const float*)d_in[1];
    const float* a = (const float*)d_in[2];
    const float* b = (const float*)d_in[3];
    const float* c = (const float*)d_in[4];

    float* xn  = (float*)d_out;                       // [BATCH][DH]
    float* out = xn + (size_t)BATCH * DH;             // [BATCH][DOUT]

    char* ws = (char*)d_ws;
    float*  decay = (float*)ws;                       // 512 f32
    ushort* bhi = (ushort*)(ws + 4096);               // 128KB frag-linear B
    ushort* chi = bhi + 128 * 512;                    // 128KB frag-linear C
    float*  bcf = (float*)(ws + 4096 + 2 * 131072);   // 64KB
    ushort* bch = (ushort*)(ws + 4096 + 2 * 131072 + 65536);  // 32KB

    prep1_kernel<<<dim3(129), dim3(256), 0, stream>>>(a, b, c, decay, bhi, chi, bcf);
    prep2_kernel<<<dim3(8), dim3(256), 0, stream>>>(bcf, bch);
    rnn_fused<<<dim3(BATCH / ROWS * 2), dim3(256), 0, stream>>>(u, x, decay, bhi, chi, bch, xn, out);
}

// Round 20
// 100.680 us; speedup vs baseline: 2.7644x; 1.3580x over previous
//
#include <hip/hip_runtime.h>
#include <hip/hip_bf16.h>

#define BATCH 65536
#define DIN   128
#define DH    512
#define DOUT  128
#define ROWS  32

typedef __attribute__((ext_vector_type(4))) float f32x4;
typedef __attribute__((ext_vector_type(8))) short s16x8;

__device__ __forceinline__ ushort f32_to_bf16_rn(float f) {
    uint32_t u = __float_as_uint(f);
    uint32_t r = (u + 0x7FFFu + ((u >> 16) & 1u)) >> 16;
    return (ushort)r;
}
__device__ __forceinline__ float bf16_to_f32(ushort h) {
    return __uint_as_float(((uint32_t)h) << 16);
}
__device__ __forceinline__ f32x4 mfma16(s16x8 a, s16x8 b, f32x4 c) {
    return __builtin_amdgcn_mfma_f32_16x16x32_bf16(a, b, c, 0, 0, 0);
}
// two f32x4 -> one s16x8 (plain bf16 RN; tolerance 8.0 >> bf16 GEMM error)
__device__ __forceinline__ s16x8 cvt8(f32x4 v0, f32x4 v1) {
    s16x8 r;
#pragma unroll
    for (int j = 0; j < 4; ++j) r[j] = (short)f32_to_bf16_rn(v0[j]);
#pragma unroll
    for (int j = 0; j < 4; ++j) r[4 + j] = (short)f32_to_bf16_rn(v1[j]);
    return r;
}

// ---------------------------------------------------------------------------
// prep: blk0 softmax(a); blk1..64 split B,C -> bf16 frag-linear. [verified]
// perm[(f*64+lane)*8+j] = M[k][col], k = ks*32+(lane>>4)*8+j,
// col = cg*16+(lane&15). B: f=cg*4+ks (cg<32). C: f=cg*16+ksg (cg<8,ksg<16).
// ---------------------------------------------------------------------------
__global__ void prep_kernel(const float* __restrict__ a,
                            const float* __restrict__ b,
                            const float* __restrict__ c,
                            float* __restrict__ decay,
                            ushort* __restrict__ bhi,
                            ushort* __restrict__ chi)
{
    const int t = threadIdx.x;
    if (blockIdx.x == 0) {
        __shared__ float red[256];
        float v0 = a[t], v1 = a[t + 256];
        red[t] = fmaxf(v0, v1);
        __syncthreads();
        for (int s = 128; s > 0; s >>= 1) {
            if (t < s) red[t] = fmaxf(red[t], red[t + s]);
            __syncthreads();
        }
        float M = red[0];
        __syncthreads();
        float e0 = expf(v0 - M), e1 = expf(v1 - M);
        red[t] = e0 + e1;
        __syncthreads();
        for (int s = 128; s > 0; s >>= 1) {
            if (t < s) red[t] += red[t + s];
            __syncthreads();
        }
        float S = red[0];
        decay[t]       = e0 / S;
        decay[t + 256] = e1 / S;
    } else {
        const int p = (blockIdx.x - 1) * 256 + t;
        const int mtx = p >> 13;
        const int q = p & 8191;
        const int f = q >> 6;
        const int l = q & 63;
        s16x8 hi;
        if (mtx == 0) {
            const int cg = f >> 2, ks = f & 3;
            const int col = cg * 16 + (l & 15);
            const int kbase = ks * 32 + (l >> 4) * 8;
#pragma unroll
            for (int j = 0; j < 8; ++j)
                hi[j] = (short)f32_to_bf16_rn(b[(size_t)(kbase + j) * DH + col]);
            *(s16x8*)(bhi + (size_t)q * 8) = hi;
        } else {
            const int cg = f >> 4, ks = f & 15;
            const int col = cg * 16 + (l & 15);
            const int kbase = ks * 32 + (l >> 4) * 8;
#pragma unroll
            for (int j = 0; j < 8; ++j)
                hi[j] = (short)f32_to_bf16_rn(c[(size_t)(kbase + j) * DOUT + col]);
            *(s16x8*)(chi + (size_t)q * 8) = hi;
        }
    }
}

// ---------------------------------------------------------------------------
// fused v15: v12 EXCEPT the xn store moves AFTER __syncthreads.
// Rationale: __syncthreads drains vmcnt(0); v12 issued 16 xn stores
// immediately before it -> full store-latency stall every chunk. Post-
// barrier, stores get the whole next chunk body (~800cy: GEMM2 + cF issue
// + GEMM1 + prefetch) to retire before the next barrier's drain.
// Everything else byte-identical to v12 (103.3 us, best measured):
// block 32 rows, 4 waves, 8 chunks x 64 cols; LDS 16KB (A 8KB + X dbuf);
// cF issued first; GEMM1 from bF regs; B/x(ct+1) issued pre-barrier;
// X[ct&1] <- bf16; one barrier/chunk; GEMM2 from cF regs.
// ---------------------------------------------------------------------------
__global__ __launch_bounds__(256, 4)
void rnn_fused(const float* __restrict__ u, const float* __restrict__ x,
               const float* __restrict__ decay,
               const ushort* __restrict__ bhi, const ushort* __restrict__ chi,
               float* __restrict__ xn, float* __restrict__ out)
{
    __shared__ __align__(16) char smem[16384];
    ushort* Ah = (ushort*)smem;             // [32][128] bf16, swz, 8KB

    const int t = threadIdx.x;
    const int lane = t & 63, wc = t >> 6;
    const int cl = lane & 15, hk = lane >> 4;
    const int row0 = blockIdx.x * ROWS;

    {   // stage A: u[32][128] f32 -> bf16 swizzled; 64B/thread coalesced
        const int r = t >> 3;
        const int kb = (t & 7) * 2;
#pragma unroll
        for (int i = 0; i < 2; ++i) {
            const float* src = u + (size_t)(row0 + r) * DIN + (kb + i) * 8;
            f32x4 v0 = *(const f32x4*)src;
            f32x4 v1 = *(const f32x4*)(src + 4);
            const int byte = (r * 256 + (kb + i) * 16) ^ ((r & 7) << 4);
            *(s16x8*)((char*)Ah + byte) = cvt8(v0, v1);
        }
    }

    // prologue: bF = B(0) frags; xv = x(0); dvc = decay(0)   (batched issue)
    s16x8 bF[4], bFn[4];
#pragma unroll
    for (int ks = 0; ks < 4; ++ks)
        bF[ks] = *(const s16x8*)(bhi + (size_t)(wc * 4 + ks) * 512 + lane * 8);

    float xv[2][4], xvn[2][4], dvc, dvn;
    dvc = decay[wc * 16 + cl];
#pragma unroll
    for (int mf = 0; mf < 2; ++mf)
#pragma unroll
        for (int j = 0; j < 4; ++j)
            xv[mf][j] = x[(size_t)(row0 + mf * 16 + 4 * hk + j) * DH + wc * 16 + cl];

    __syncthreads();   // A visible

    f32x4 acc2[2][2];
#pragma unroll
    for (int mf = 0; mf < 2; ++mf)
#pragma unroll
        for (int nf = 0; nf < 2; ++nf)
            acc2[mf][nf] = (f32x4){0.f, 0.f, 0.f, 0.f};

    for (int ct = 0; ct < 8; ++ct) {
        char* Xh = smem + 8192 + (ct & 1) * 4096;   // [32][64] bf16, swz

        // ---- issue C(ct) frag loads FIRST (consumed at chunk end)
        s16x8 cF[2][2];
#pragma unroll
        for (int ks2 = 0; ks2 < 2; ++ks2)
#pragma unroll
            for (int nf = 0; nf < 2; ++nf)
                cF[ks2][nf] = *(const s16x8*)(chi +
                    (size_t)((wc * 2 + nf) * 16 + ct * 2 + ks2) * 512 + lane * 8);

        // ---- GEMM1: acc1 = u @ B-chunk from bF regs (LDS A + MFMA only)
        f32x4 acc1[2];
        acc1[0] = (f32x4){0.f, 0.f, 0.f, 0.f};
        acc1[1] = (f32x4){0.f, 0.f, 0.f, 0.f};
#pragma unroll
        for (int ks = 0; ks < 4; ++ks) {
            const int ko = ks * 32 + hk * 8;
            s16x8 ah[2];
#pragma unroll
            for (int mf = 0; mf < 2; ++mf) {
                const int r = mf * 16 + cl;
                const int byte = (r * 256 + ko * 2) ^ ((r & 7) << 4);
                ah[mf] = *(const s16x8*)((const char*)Ah + byte);
            }
#pragma unroll
            for (int mf = 0; mf < 2; ++mf) acc1[mf] = mfma16(ah[mf], bF[ks], acc1[mf]);
        }

        // ---- issue B(ct+1) + x(ct+1) (complete during epilogue/barrier)
        if (ct < 7) {
#pragma unroll
            for (int ks = 0; ks < 4; ++ks)
                bFn[ks] = *(const s16x8*)(bhi +
                    (size_t)(((ct + 1) * 4 + wc) * 4 + ks) * 512 + lane * 8);
            const int ncol = (ct + 1) * 64 + wc * 16 + cl;
            dvn = decay[ncol];
#pragma unroll
            for (int mf = 0; mf < 2; ++mf)
#pragma unroll
                for (int j = 0; j < 4; ++j)
                    xvn[mf][j] = x[(size_t)(row0 + mf * 16 + 4 * hk + j) * DH + ncol];
        }

        // ---- X[ct&1] <- bf16(acc1 + dv*x) (LDS only; xn store deferred)
        {
#pragma unroll
            for (int mf = 0; mf < 2; ++mf) {
#pragma unroll
                for (int j = 0; j < 4; ++j) {
                    const int rl = mf * 16 + 4 * hk + j;
                    const float v = acc1[mf][j] + dvc * xv[mf][j];
                    const int cbyte = (rl * 128 + (wc * 16 + cl) * 2) ^ ((rl & 7) << 4);
                    *(ushort*)(Xh + cbyte) = f32_to_bf16_rn(v);
                }
            }
        }

        __syncthreads();   // single barrier: X[ct&1] visible to all waves

        // ---- xn store AFTER the barrier: retires during GEMM2 + next chunk
        {
            const int col = ct * 64 + wc * 16 + cl;
#pragma unroll
            for (int mf = 0; mf < 2; ++mf)
#pragma unroll
                for (int j = 0; j < 4; ++j)
                    xn[(size_t)(row0 + mf * 16 + 4 * hk + j) * DH + col] =
                        acc1[mf][j] + dvc * xv[mf][j];
        }

        // ---- GEMM2: acc2 += X @ C-chunk from cF regs
#pragma unroll
        for (int ks2 = 0; ks2 < 2; ++ks2) {
            const int ko = ks2 * 32 + hk * 8;
            s16x8 ah2[2];
#pragma unroll
            for (int mf = 0; mf < 2; ++mf) {
                const int r = mf * 16 + cl;
                const int byte = (r * 128 + ko * 2) ^ ((r & 7) << 4);
                ah2[mf] = *(const s16x8*)((const char*)Xh + byte);
            }
#pragma unroll
            for (int nf = 0; nf < 2; ++nf)
#pragma unroll
                for (int mf = 0; mf < 2; ++mf)
                    acc2[mf][nf] = mfma16(ah2[mf], cF[ks2][nf], acc2[mf][nf]);
        }

        // ---- rotate prefetched state
#pragma unroll
        for (int ks = 0; ks < 4; ++ks) bF[ks] = bFn[ks];
        dvc = dvn;
#pragma unroll
        for (int mf = 0; mf < 2; ++mf)
#pragma unroll
            for (int j = 0; j < 4; ++j) xv[mf][j] = xvn[mf][j];
    }

    // ---- final: store out[32 x 128]; wave covers cols [wc*32, +32)
#pragma unroll
    for (int nf = 0; nf < 2; ++nf) {
        const int ocol = wc * 32 + nf * 16 + cl;
#pragma unroll
        for (int mf = 0; mf < 2; ++mf) {
#pragma unroll
            for (int j = 0; j < 4; ++j) {
                const int rl = mf * 16 + 4 * hk + j;
                out[(size_t)(row0 + rl) * DOUT + ocol] = acc2[mf][nf][j];
            }
        }
    }
}

extern "C" void kernel_launch(void* const* d_in, const int* in_sizes, int n_in,
                              void* d_out, int out_size, void* d_ws, size_t ws_size,
                              hipStream_t stream)
{
    const float* x = (const float*)d_in[0];
    const float* u = (const float*)d_in[1];
    const float* a = (const float*)d_in[2];
    const float* b = (const float*)d_in[3];
    const float* c = (const float*)d_in[4];

    float* xn  = (float*)d_out;                       // [BATCH][DH]
    float* out = xn + (size_t)BATCH * DH;             // [BATCH][DOUT]

    char* ws = (char*)d_ws;
    float*  decay = (float*)ws;                       // 512 f32
    ushort* bhi = (ushort*)(ws + 4096);               // 128KB frag-linear B
    ushort* chi = bhi + 128 * 512;                    // 128KB frag-linear C

    prep_kernel<<<dim3(65), dim3(256), 0, stream>>>(a, b, c, decay, bhi, chi);
    rnn_fused<<<dim3(BATCH / ROWS), dim3(256), 0, stream>>>(u, x, decay, bhi, chi, xn, out);
}